// Round 9
// baseline (689.916 us; speedup 1.0000x reference)
//
#include <hip/hip_runtime.h>
#include <cstddef>

// Problem constants (from reference setup_inputs).
constexpr int N_  = 32;
constexpr int H_  = 16;
constexpr int E_  = 128;   // = D
constexpr int D_  = 128;
constexpr int S_  = 2047;
constexpr int SP1 = 2048;  // S+1
constexpr int NH  = N_ * H_;

constexpr int ROWS_PER_BLOCK = 256;
constexpr int CHUNKS = SP1 / ROWS_PER_BLOCK;  // 8
constexpr int COLCH  = SP1 / 256;             // 8 column-chunks for k2a/k2c

typedef float vfloat4 __attribute__((ext_vector_type(4)));

// ---------------------------------------------------------------------------
// k1: stream keys_cache + appended key -> keys_out (cached loads, PLAIN
// stores this round — A/B vs nt), and compute scores in-pass.
// Wave-sequential mapping: each wave owns a contiguous 64-row (32KB) strip.
// ---------------------------------------------------------------------------
__global__ __launch_bounds__(256) void k1_keys_scores(
    const float* __restrict__ query, const float* __restrict__ key,
    const float* __restrict__ keys_cache,
    float* __restrict__ keys_out, float* __restrict__ scores)
{
  __shared__ float sc[ROWS_PER_BLOCK];
  const int bid   = blockIdx.x;
  const int nh    = bid / CHUNKS;
  const int chunk = bid % CHUNKS;
  const int tid   = threadIdx.x;
  const int wave  = tid >> 6;
  const int lane  = tid & 63;
  const int half  = lane >> 5;
  const int lcol  = lane & 31;
  const int rbase = wave * 64 + half;  // contiguous 64-row strip per wave

  const vfloat4 q4 = *reinterpret_cast<const vfloat4*>(query + (size_t)nh * E_ + lcol * 4);

  #pragma unroll 8
  for (int it = 0; it < 32; ++it) {
    const int r = rbase + it * 2;
    const int s = chunk * ROWS_PER_BLOCK + r;
    const float* src = (s < S_) ? (keys_cache + ((size_t)nh * S_ + s) * E_)
                                : (key + (size_t)nh * E_);
    vfloat4 k4 = *reinterpret_cast<const vfloat4*>(src + lcol * 4);
    *reinterpret_cast<vfloat4*>(keys_out + ((size_t)nh * SP1 + s) * E_ + lcol * 4) = k4;

    float p = q4.x * k4.x + q4.y * k4.y + q4.z * k4.z + q4.w * k4.w;
    p += __shfl_xor(p, 1);
    p += __shfl_xor(p, 2);
    p += __shfl_xor(p, 4);
    p += __shfl_xor(p, 8);
    p += __shfl_xor(p, 16);
    if (lcol == 0) sc[r] = p;
  }
  __syncthreads();
  scores[(size_t)nh * SP1 + chunk * ROWS_PER_BLOCK + tid] = sc[tid];
}

// ---------------------------------------------------------------------------
// k2a: per (n, col-chunk) block, each thread owns one s column: read the 16
// head scores once, pre-mix, block-reduce per-g max and sum-exp -> stats.
// ---------------------------------------------------------------------------
__global__ __launch_bounds__(256) void k2a_stats(
    const float* __restrict__ scores, const float* __restrict__ w_pre,
    float* __restrict__ blkstats)
{
  __shared__ float wp[H_ * H_];
  __shared__ float red[4][H_];
  __shared__ float bmax[H_];
  const int n   = blockIdx.x >> 3;
  const int cc  = blockIdx.x & 7;
  const int tid = threadIdx.x;
  const int wave = tid >> 6;
  const int lane = tid & 63;
  const float temp = 0.08838834764831845f;  // 1/sqrt(128)

  wp[tid] = w_pre[tid];
  __syncthreads();

  const float* base = scores + (size_t)n * H_ * SP1 + cc * 256 + tid;
  float sc[H_];
  #pragma unroll
  for (int h = 0; h < H_; ++h) sc[h] = base[(size_t)h * SP1];

  float mx[H_];
  #pragma unroll
  for (int g = 0; g < H_; ++g) {
    float acc = 0.0f;
    #pragma unroll
    for (int h = 0; h < H_; ++h) acc += wp[g * H_ + h] * sc[h];
    mx[g] = acc * temp;
  }

  #pragma unroll
  for (int g = 0; g < H_; ++g) {
    float v = mx[g];
    #pragma unroll
    for (int m = 1; m <= 32; m <<= 1) v = fmaxf(v, __shfl_xor(v, m));
    if (lane == 0) red[wave][g] = v;
  }
  __syncthreads();
  if (tid < H_) {
    float v = fmaxf(fmaxf(red[0][tid], red[1][tid]), fmaxf(red[2][tid], red[3][tid]));
    bmax[tid] = v;
    blkstats[((size_t)(n * COLCH + cc) * 2 + 0) * H_ + tid] = v;
  }
  __syncthreads();

  #pragma unroll
  for (int g = 0; g < H_; ++g) {
    float e = __expf(mx[g] - bmax[g]);
    #pragma unroll
    for (int m = 1; m <= 32; m <<= 1) e += __shfl_xor(e, m);
    if (lane == 0) red[wave][g] = e;
  }
  __syncthreads();
  if (tid < H_) {
    blkstats[((size_t)(n * COLCH + cc) * 2 + 1) * H_ + tid] =
        red[0][tid] + red[1][tid] + red[2][tid] + red[3][tid];
  }
}

// ---------------------------------------------------------------------------
// k2c: combine per-block stats -> per-(n,g) max/denom, re-read scores once,
// compute P[h], post-mix -> A2[n,g,s], written once.
// ---------------------------------------------------------------------------
__global__ __launch_bounds__(256) void k2c_a2(
    const float* __restrict__ scores, const float* __restrict__ blkstats,
    const float* __restrict__ w_pre, const float* __restrict__ w_post,
    float* __restrict__ a2out)
{
  __shared__ float wp[H_ * H_];
  __shared__ float wq[H_ * H_];
  __shared__ float mg[H_];
  __shared__ float ig[H_];
  const int n   = blockIdx.x >> 3;
  const int cc  = blockIdx.x & 7;
  const int tid = threadIdx.x;
  const float temp = 0.08838834764831845f;

  wp[tid] = w_pre[tid];
  wq[tid] = w_post[tid];
  if (tid < H_) {
    float bm[COLCH], bs[COLCH];
    #pragma unroll
    for (int c = 0; c < COLCH; ++c) {
      bm[c] = blkstats[((size_t)(n * COLCH + c) * 2 + 0) * H_ + tid];
      bs[c] = blkstats[((size_t)(n * COLCH + c) * 2 + 1) * H_ + tid];
    }
    float m = bm[0];
    #pragma unroll
    for (int c = 1; c < COLCH; ++c) m = fmaxf(m, bm[c]);
    float den = 0.0f;
    #pragma unroll
    for (int c = 0; c < COLCH; ++c) den += bs[c] * __expf(bm[c] - m);
    mg[tid] = m;
    ig[tid] = 1.0f / den;
  }
  __syncthreads();

  const float* base = scores + (size_t)n * H_ * SP1 + cc * 256 + tid;
  float sc[H_];
  #pragma unroll
  for (int h = 0; h < H_; ++h) sc[h] = base[(size_t)h * SP1];

  float P[H_];
  #pragma unroll
  for (int h = 0; h < H_; ++h) {
    float acc = 0.0f;
    #pragma unroll
    for (int h2 = 0; h2 < H_; ++h2) acc += wp[h * H_ + h2] * sc[h2];
    P[h] = __expf(acc * temp - mg[h]) * ig[h];
  }

  #pragma unroll
  for (int g = 0; g < H_; ++g) {
    float a = 0.0f;
    #pragma unroll
    for (int h = 0; h < H_; ++h) a += wq[g * H_ + h] * P[h];
    a2out[((size_t)(n * H_ + g)) * SP1 + cc * 256 + tid] = a;
  }
}

// ---------------------------------------------------------------------------
// k3: per (nh, chunk) block: load this chunk's 256 A2 weights (coalesced),
// stream values_cache + appended value -> values_out (cached loads, PLAIN
// stores this round), accumulate partial[d] = sum_s A2[s]*v[s,d] in regs,
// reduce through LDS, publish partials (agent scope), then the LAST block
// per nh (fetch_add == 7; no spinning) reduces the 8 partials in fixed
// order and writes V[nh,:]. Deterministic.
// ---------------------------------------------------------------------------
__global__ __launch_bounds__(256) void k3_values(
    const float* __restrict__ value, const float* __restrict__ values_cache,
    const float* __restrict__ a2buf, float* __restrict__ values_out,
    float* __restrict__ partials, int* __restrict__ ctr,
    float* __restrict__ v_out)
{
  __shared__ float lds[8][128];
  __shared__ float a2[ROWS_PER_BLOCK];
  __shared__ int lastflag;
  const int bid   = blockIdx.x;
  const int nh    = bid / CHUNKS;
  const int chunk = bid % CHUNKS;
  const int tid   = threadIdx.x;
  const int wave  = tid >> 6;
  const int lane  = tid & 63;
  const int half  = lane >> 5;
  const int lcol  = lane & 31;
  const int group = wave * 2 + half;
  const int rbase = wave * 64 + half;  // contiguous 64-row strip per wave

  a2[tid] = a2buf[(size_t)nh * SP1 + chunk * ROWS_PER_BLOCK + tid];
  __syncthreads();

  float accx = 0.0f, accy = 0.0f, accz = 0.0f, accw = 0.0f;

  #pragma unroll 8
  for (int it = 0; it < 32; ++it) {
    const int r = rbase + it * 2;
    const int s = chunk * ROWS_PER_BLOCK + r;
    const float* src = (s < S_) ? (values_cache + ((size_t)nh * S_ + s) * D_)
                                : (value + (size_t)nh * D_);
    vfloat4 v4 = *reinterpret_cast<const vfloat4*>(src + lcol * 4);
    *reinterpret_cast<vfloat4*>(values_out + ((size_t)nh * SP1 + s) * D_ + lcol * 4) = v4;

    const float w = a2[r];  // broadcast within half-wave: conflict-free
    accx += w * v4.x;
    accy += w * v4.y;
    accz += w * v4.z;
    accw += w * v4.w;
  }

  lds[group][lcol * 4 + 0] = accx;
  lds[group][lcol * 4 + 1] = accy;
  lds[group][lcol * 4 + 2] = accz;
  lds[group][lcol * 4 + 3] = accw;
  __syncthreads();
  if (tid < 128) {
    float sum = 0.0f;
    #pragma unroll
    for (int gq = 0; gq < 8; ++gq) sum += lds[gq][tid];
    __hip_atomic_store(&partials[(size_t)bid * 128 + tid], sum,
                       __ATOMIC_RELAXED, __HIP_MEMORY_SCOPE_AGENT);
  }
  __syncthreads();

  if (tid == 0) {
    const int old = __hip_atomic_fetch_add(&ctr[nh], 1, __ATOMIC_ACQ_REL,
                                           __HIP_MEMORY_SCOPE_AGENT);
    lastflag = (old == CHUNKS - 1);
  }
  __syncthreads();

  if (lastflag && tid < 128) {
    float s = 0.0f;
    #pragma unroll
    for (int c = 0; c < CHUNKS; ++c)
      s += __hip_atomic_load(&partials[((size_t)(nh * CHUNKS + c)) * 128 + tid],
                             __ATOMIC_RELAXED, __HIP_MEMORY_SCOPE_AGENT);
    v_out[(size_t)nh * 128 + tid] = s;
  }
}

extern "C" void kernel_launch(void* const* d_in, const int* in_sizes, int n_in,
                              void* d_out, int out_size, void* d_ws, size_t ws_size,
                              hipStream_t stream) {
  const float* query        = (const float*)d_in[0];
  const float* key          = (const float*)d_in[1];
  const float* value        = (const float*)d_in[2];
  const float* keys_cache   = (const float*)d_in[3];
  const float* values_cache = (const float*)d_in[4];
  const float* w_pre        = (const float*)d_in[5];
  const float* w_post       = (const float*)d_in[6];

  float* out = (float*)d_out;
  float* v_out      = out;                                  // [N,H,D]
  float* keys_out   = out + (size_t)NH * D_;                // [N,H,SP1,E]
  float* values_out = keys_out + (size_t)NH * SP1 * E_;     // [N,H,SP1,D]

  float* buf0     = (float*)d_ws;                 // raw scores   [NH,SP1]
  float* a2buf    = buf0 + (size_t)NH * SP1;      // A2           [NH,SP1]
  float* blkstats = a2buf + (size_t)NH * SP1;     // [N,COLCH,2,H]
  float* partials = blkstats + (size_t)N_ * COLCH * 2 * H_;  // [NH*CHUNKS,128]
  int*   ctrs     = (int*)(partials + (size_t)NH * CHUNKS * 128);  // [NH]

  // Zero the completion counters (stream-ordered, graph-capture safe).
  hipMemsetAsync(ctrs, 0, NH * sizeof(int), stream);

  // 1. keys copy + QK scores
  k1_keys_scores<<<NH * CHUNKS, 256, 0, stream>>>(query, key, keys_cache,
                                                  keys_out, buf0);
  // 2a. per-block softmax stats (scores read once)
  k2a_stats<<<N_ * COLCH, 256, 0, stream>>>(buf0, w_pre, blkstats);
  // 2c. combine stats + compute post-mixed A2 (scores read once more)
  k2c_a2<<<N_ * COLCH, 256, 0, stream>>>(buf0, blkstats, w_pre, w_post, a2buf);
  // 3. values copy + readout partials + last-block V reduction
  k3_values<<<NH * CHUNKS, 256, 0, stream>>>(value, values_cache, a2buf,
                                             values_out, partials, ctrs, v_out);
}

// Round 10
// 452.381 us; speedup vs baseline: 1.5251x; 1.5251x over previous
//
#include <hip/hip_runtime.h>
#include <cstddef>

// Problem constants (from reference setup_inputs).
constexpr int N_  = 32;
constexpr int H_  = 16;
constexpr int E_  = 128;   // = D
constexpr int D_  = 128;
constexpr int S_  = 2047;
constexpr int SP1 = 2048;  // S+1
constexpr int NH  = N_ * H_;

constexpr int ROWS_PER_BLOCK = 256;
constexpr int CHUNKS = SP1 / ROWS_PER_BLOCK;  // 8
constexpr int COLCH  = SP1 / 256;             // 8 column-chunks for k2a/k2c

typedef float vfloat4 __attribute__((ext_vector_type(4)));

// ---------------------------------------------------------------------------
// k1: stream keys_cache + appended key -> keys_out, compute scores in-pass.
// Wave-sequential mapping: each wave owns a contiguous 64-row (32KB) strip.
// THIS ROUND'S ISOLATED A/B: plain cached stores (was nt in the 433us run).
// NO atomics anywhere (R7/R9 lesson: agent-scope fences cost ~250us).
// ---------------------------------------------------------------------------
__global__ __launch_bounds__(256) void k1_keys_scores(
    const float* __restrict__ query, const float* __restrict__ key,
    const float* __restrict__ keys_cache,
    float* __restrict__ keys_out, float* __restrict__ scores)
{
  __shared__ float sc[ROWS_PER_BLOCK];
  const int bid   = blockIdx.x;
  const int nh    = bid / CHUNKS;
  const int chunk = bid % CHUNKS;
  const int tid   = threadIdx.x;
  const int wave  = tid >> 6;
  const int lane  = tid & 63;
  const int half  = lane >> 5;
  const int lcol  = lane & 31;
  const int rbase = wave * 64 + half;  // contiguous 64-row strip per wave

  const vfloat4 q4 = *reinterpret_cast<const vfloat4*>(query + (size_t)nh * E_ + lcol * 4);

  #pragma unroll 8
  for (int it = 0; it < 32; ++it) {
    const int r = rbase + it * 2;
    const int s = chunk * ROWS_PER_BLOCK + r;
    const float* src = (s < S_) ? (keys_cache + ((size_t)nh * S_ + s) * E_)
                                : (key + (size_t)nh * E_);
    vfloat4 k4 = *reinterpret_cast<const vfloat4*>(src + lcol * 4);
    *reinterpret_cast<vfloat4*>(keys_out + ((size_t)nh * SP1 + s) * E_ + lcol * 4) = k4;

    float p = q4.x * k4.x + q4.y * k4.y + q4.z * k4.z + q4.w * k4.w;
    p += __shfl_xor(p, 1);
    p += __shfl_xor(p, 2);
    p += __shfl_xor(p, 4);
    p += __shfl_xor(p, 8);
    p += __shfl_xor(p, 16);
    if (lcol == 0) sc[r] = p;
  }
  __syncthreads();
  scores[(size_t)nh * SP1 + chunk * ROWS_PER_BLOCK + tid] = sc[tid];
}

// ---------------------------------------------------------------------------
// k2a: per (n, col-chunk) block, each thread owns one s column: read the 16
// head scores once, pre-mix, block-reduce per-g max and sum-exp -> stats.
// ---------------------------------------------------------------------------
__global__ __launch_bounds__(256) void k2a_stats(
    const float* __restrict__ scores, const float* __restrict__ w_pre,
    float* __restrict__ blkstats)
{
  __shared__ float wp[H_ * H_];
  __shared__ float red[4][H_];
  __shared__ float bmax[H_];
  const int n   = blockIdx.x >> 3;
  const int cc  = blockIdx.x & 7;
  const int tid = threadIdx.x;
  const int wave = tid >> 6;
  const int lane = tid & 63;
  const float temp = 0.08838834764831845f;  // 1/sqrt(128)

  wp[tid] = w_pre[tid];
  __syncthreads();

  const float* base = scores + (size_t)n * H_ * SP1 + cc * 256 + tid;
  float sc[H_];
  #pragma unroll
  for (int h = 0; h < H_; ++h) sc[h] = base[(size_t)h * SP1];

  float mx[H_];
  #pragma unroll
  for (int g = 0; g < H_; ++g) {
    float acc = 0.0f;
    #pragma unroll
    for (int h = 0; h < H_; ++h) acc += wp[g * H_ + h] * sc[h];
    mx[g] = acc * temp;
  }

  #pragma unroll
  for (int g = 0; g < H_; ++g) {
    float v = mx[g];
    #pragma unroll
    for (int m = 1; m <= 32; m <<= 1) v = fmaxf(v, __shfl_xor(v, m));
    if (lane == 0) red[wave][g] = v;
  }
  __syncthreads();
  if (tid < H_) {
    float v = fmaxf(fmaxf(red[0][tid], red[1][tid]), fmaxf(red[2][tid], red[3][tid]));
    bmax[tid] = v;
    blkstats[((size_t)(n * COLCH + cc) * 2 + 0) * H_ + tid] = v;
  }
  __syncthreads();

  #pragma unroll
  for (int g = 0; g < H_; ++g) {
    float e = __expf(mx[g] - bmax[g]);
    #pragma unroll
    for (int m = 1; m <= 32; m <<= 1) e += __shfl_xor(e, m);
    if (lane == 0) red[wave][g] = e;
  }
  __syncthreads();
  if (tid < H_) {
    blkstats[((size_t)(n * COLCH + cc) * 2 + 1) * H_ + tid] =
        red[0][tid] + red[1][tid] + red[2][tid] + red[3][tid];
  }
}

// ---------------------------------------------------------------------------
// k2c: combine per-block stats -> per-(n,g) max/denom, re-read scores once,
// compute P[h], post-mix -> A2[n,g,s], written once.
// ---------------------------------------------------------------------------
__global__ __launch_bounds__(256) void k2c_a2(
    const float* __restrict__ scores, const float* __restrict__ blkstats,
    const float* __restrict__ w_pre, const float* __restrict__ w_post,
    float* __restrict__ a2out)
{
  __shared__ float wp[H_ * H_];
  __shared__ float wq[H_ * H_];
  __shared__ float mg[H_];
  __shared__ float ig[H_];
  const int n   = blockIdx.x >> 3;
  const int cc  = blockIdx.x & 7;
  const int tid = threadIdx.x;
  const float temp = 0.08838834764831845f;

  wp[tid] = w_pre[tid];
  wq[tid] = w_post[tid];
  if (tid < H_) {
    float bm[COLCH], bs[COLCH];
    #pragma unroll
    for (int c = 0; c < COLCH; ++c) {
      bm[c] = blkstats[((size_t)(n * COLCH + c) * 2 + 0) * H_ + tid];
      bs[c] = blkstats[((size_t)(n * COLCH + c) * 2 + 1) * H_ + tid];
    }
    float m = bm[0];
    #pragma unroll
    for (int c = 1; c < COLCH; ++c) m = fmaxf(m, bm[c]);
    float den = 0.0f;
    #pragma unroll
    for (int c = 0; c < COLCH; ++c) den += bs[c] * __expf(bm[c] - m);
    mg[tid] = m;
    ig[tid] = 1.0f / den;
  }
  __syncthreads();

  const float* base = scores + (size_t)n * H_ * SP1 + cc * 256 + tid;
  float sc[H_];
  #pragma unroll
  for (int h = 0; h < H_; ++h) sc[h] = base[(size_t)h * SP1];

  float P[H_];
  #pragma unroll
  for (int h = 0; h < H_; ++h) {
    float acc = 0.0f;
    #pragma unroll
    for (int h2 = 0; h2 < H_; ++h2) acc += wp[h * H_ + h2] * sc[h2];
    P[h] = __expf(acc * temp - mg[h]) * ig[h];
  }

  #pragma unroll
  for (int g = 0; g < H_; ++g) {
    float a = 0.0f;
    #pragma unroll
    for (int h = 0; h < H_; ++h) a += wq[g * H_ + h] * P[h];
    a2out[((size_t)(n * H_ + g)) * SP1 + cc * 256 + tid] = a;
  }
}

// ---------------------------------------------------------------------------
// k3: per (nh, chunk) block: load this chunk's 256 A2 weights (coalesced),
// stream values_cache + appended value -> values_out (plain stores this
// round), accumulate partial[d] = sum_s A2[s]*v[s,d] in registers; reduce
// through LDS to per-block partials (deterministic, no atomics).
// ---------------------------------------------------------------------------
__global__ __launch_bounds__(256) void k3_values(
    const float* __restrict__ value, const float* __restrict__ values_cache,
    const float* __restrict__ a2buf, float* __restrict__ values_out,
    float* __restrict__ partials)
{
  __shared__ float lds[8][128];
  __shared__ float a2[ROWS_PER_BLOCK];
  const int bid   = blockIdx.x;
  const int nh    = bid / CHUNKS;
  const int chunk = bid % CHUNKS;
  const int tid   = threadIdx.x;
  const int wave  = tid >> 6;
  const int lane  = tid & 63;
  const int half  = lane >> 5;
  const int lcol  = lane & 31;
  const int group = wave * 2 + half;
  const int rbase = wave * 64 + half;  // contiguous 64-row strip per wave

  a2[tid] = a2buf[(size_t)nh * SP1 + chunk * ROWS_PER_BLOCK + tid];
  __syncthreads();

  float accx = 0.0f, accy = 0.0f, accz = 0.0f, accw = 0.0f;

  #pragma unroll 8
  for (int it = 0; it < 32; ++it) {
    const int r = rbase + it * 2;
    const int s = chunk * ROWS_PER_BLOCK + r;
    const float* src = (s < S_) ? (values_cache + ((size_t)nh * S_ + s) * D_)
                                : (value + (size_t)nh * D_);
    vfloat4 v4 = *reinterpret_cast<const vfloat4*>(src + lcol * 4);
    *reinterpret_cast<vfloat4*>(values_out + ((size_t)nh * SP1 + s) * D_ + lcol * 4) = v4;

    const float w = a2[r];  // broadcast within half-wave: conflict-free
    accx += w * v4.x;
    accy += w * v4.y;
    accz += w * v4.z;
    accw += w * v4.w;
  }

  lds[group][lcol * 4 + 0] = accx;
  lds[group][lcol * 4 + 1] = accy;
  lds[group][lcol * 4 + 2] = accz;
  lds[group][lcol * 4 + 3] = accw;
  __syncthreads();
  if (tid < 128) {
    float sum = 0.0f;
    #pragma unroll
    for (int gq = 0; gq < 8; ++gq) sum += lds[gq][tid];
    partials[(size_t)bid * 128 + tid] = sum;
  }
}

// ---------------------------------------------------------------------------
// k4: reduce per-chunk partials into V output. One thread per (n,h,d).
// ---------------------------------------------------------------------------
__global__ __launch_bounds__(256) void k4_reduce(
    const float* __restrict__ partials, float* __restrict__ v_out)
{
  const int g = blockIdx.x * 256 + threadIdx.x;  // NH*128
  const int nh = g >> 7;
  const int d = g & 127;
  float s = 0.0f;
  #pragma unroll
  for (int c = 0; c < CHUNKS; ++c)
    s += partials[((size_t)(nh * CHUNKS + c)) * 128 + d];
  v_out[g] = s;
}

extern "C" void kernel_launch(void* const* d_in, const int* in_sizes, int n_in,
                              void* d_out, int out_size, void* d_ws, size_t ws_size,
                              hipStream_t stream) {
  const float* query        = (const float*)d_in[0];
  const float* key          = (const float*)d_in[1];
  const float* value        = (const float*)d_in[2];
  const float* keys_cache   = (const float*)d_in[3];
  const float* values_cache = (const float*)d_in[4];
  const float* w_pre        = (const float*)d_in[5];
  const float* w_post       = (const float*)d_in[6];

  float* out = (float*)d_out;
  float* v_out      = out;                                  // [N,H,D]
  float* keys_out   = out + (size_t)NH * D_;                // [N,H,SP1,E]
  float* values_out = keys_out + (size_t)NH * SP1 * E_;     // [N,H,SP1,D]

  float* buf0     = (float*)d_ws;                 // raw scores   [NH,SP1]
  float* a2buf    = buf0 + (size_t)NH * SP1;      // A2           [NH,SP1]
  float* blkstats = a2buf + (size_t)NH * SP1;     // [N,COLCH,2,H]
  float* partials = blkstats + (size_t)N_ * COLCH * 2 * H_;  // [NH*CHUNKS,128]

  // 1. keys copy + QK scores
  k1_keys_scores<<<NH * CHUNKS, 256, 0, stream>>>(query, key, keys_cache,
                                                  keys_out, buf0);
  // 2a. per-block softmax stats (scores read once)
  k2a_stats<<<N_ * COLCH, 256, 0, stream>>>(buf0, w_pre, blkstats);
  // 2c. combine stats + compute post-mixed A2 (scores read once more)
  k2c_a2<<<N_ * COLCH, 256, 0, stream>>>(buf0, blkstats, w_pre, w_post, a2buf);
  // 3. values copy + weighted readout partials (A2 read once, coalesced)
  k3_values<<<NH * CHUNKS, 256, 0, stream>>>(value, values_cache, a2buf,
                                             values_out, partials);
  // 4. chunk-reduce -> V
  k4_reduce<<<(NH * 128) / 256, 256, 0, stream>>>(partials, v_out);
}

// Round 11
// 420.999 us; speedup vs baseline: 1.6388x; 1.0745x over previous
//
#include <hip/hip_runtime.h>
#include <cstddef>

// Problem constants (from reference setup_inputs).
constexpr int N_  = 32;
constexpr int H_  = 16;
constexpr int E_  = 128;   // = D
constexpr int D_  = 128;
constexpr int S_  = 2047;
constexpr int SP1 = 2048;  // S+1
constexpr int NH  = N_ * H_;

constexpr int ROWS_PER_BLOCK = 256;
constexpr int CHUNKS = SP1 / ROWS_PER_BLOCK;  // 8
constexpr int COLCH  = SP1 / 256;             // 8 column-chunks for k2a/k2c

typedef float vfloat4 __attribute__((ext_vector_type(4)));

// ---------------------------------------------------------------------------
// k1: stream keys_cache + appended key -> keys_out. THIS ROUND'S ISOLATED
// A/B vs R8 (433us): nontemporal LOADS on the cache stream (read-once data;
// avoid L2 read-allocate pollution). nt stores kept (R8/R10 A/B: +19us win).
// Wave-sequential mapping: each wave owns a contiguous 64-row (32KB) strip.
// Scores staged in LDS, one coalesced 1KB store per block. No atomics
// anywhere (R7/R9 lesson: agent-scope fences cost ~250us).
// ---------------------------------------------------------------------------
__global__ __launch_bounds__(256) void k1_keys_scores(
    const float* __restrict__ query, const float* __restrict__ key,
    const float* __restrict__ keys_cache,
    float* __restrict__ keys_out, float* __restrict__ scores)
{
  __shared__ float sc[ROWS_PER_BLOCK];
  const int bid   = blockIdx.x;
  const int nh    = bid / CHUNKS;
  const int chunk = bid % CHUNKS;
  const int tid   = threadIdx.x;
  const int wave  = tid >> 6;
  const int lane  = tid & 63;
  const int half  = lane >> 5;
  const int lcol  = lane & 31;
  const int rbase = wave * 64 + half;  // contiguous 64-row strip per wave

  const vfloat4 q4 = *reinterpret_cast<const vfloat4*>(query + (size_t)nh * E_ + lcol * 4);

  #pragma unroll 8
  for (int it = 0; it < 32; ++it) {
    const int r = rbase + it * 2;
    const int s = chunk * ROWS_PER_BLOCK + r;
    const float* src = (s < S_) ? (keys_cache + ((size_t)nh * S_ + s) * E_)
                                : (key + (size_t)nh * E_);
    vfloat4 k4 = __builtin_nontemporal_load(
        reinterpret_cast<const vfloat4*>(src + lcol * 4));
    __builtin_nontemporal_store(k4,
        reinterpret_cast<vfloat4*>(keys_out + ((size_t)nh * SP1 + s) * E_ + lcol * 4));

    float p = q4.x * k4.x + q4.y * k4.y + q4.z * k4.z + q4.w * k4.w;
    p += __shfl_xor(p, 1);
    p += __shfl_xor(p, 2);
    p += __shfl_xor(p, 4);
    p += __shfl_xor(p, 8);
    p += __shfl_xor(p, 16);
    if (lcol == 0) sc[r] = p;
  }
  __syncthreads();
  scores[(size_t)nh * SP1 + chunk * ROWS_PER_BLOCK + tid] = sc[tid];
}

// ---------------------------------------------------------------------------
// k2a: per (n, col-chunk) block, each thread owns one s column: read the 16
// head scores once, pre-mix, block-reduce per-g max and sum-exp -> stats.
// ---------------------------------------------------------------------------
__global__ __launch_bounds__(256) void k2a_stats(
    const float* __restrict__ scores, const float* __restrict__ w_pre,
    float* __restrict__ blkstats)
{
  __shared__ float wp[H_ * H_];
  __shared__ float red[4][H_];
  __shared__ float bmax[H_];
  const int n   = blockIdx.x >> 3;
  const int cc  = blockIdx.x & 7;
  const int tid = threadIdx.x;
  const int wave = tid >> 6;
  const int lane = tid & 63;
  const float temp = 0.08838834764831845f;  // 1/sqrt(128)

  wp[tid] = w_pre[tid];
  __syncthreads();

  const float* base = scores + (size_t)n * H_ * SP1 + cc * 256 + tid;
  float sc[H_];
  #pragma unroll
  for (int h = 0; h < H_; ++h) sc[h] = base[(size_t)h * SP1];

  float mx[H_];
  #pragma unroll
  for (int g = 0; g < H_; ++g) {
    float acc = 0.0f;
    #pragma unroll
    for (int h = 0; h < H_; ++h) acc += wp[g * H_ + h] * sc[h];
    mx[g] = acc * temp;
  }

  #pragma unroll
  for (int g = 0; g < H_; ++g) {
    float v = mx[g];
    #pragma unroll
    for (int m = 1; m <= 32; m <<= 1) v = fmaxf(v, __shfl_xor(v, m));
    if (lane == 0) red[wave][g] = v;
  }
  __syncthreads();
  if (tid < H_) {
    float v = fmaxf(fmaxf(red[0][tid], red[1][tid]), fmaxf(red[2][tid], red[3][tid]));
    bmax[tid] = v;
    blkstats[((size_t)(n * COLCH + cc) * 2 + 0) * H_ + tid] = v;
  }
  __syncthreads();

  #pragma unroll
  for (int g = 0; g < H_; ++g) {
    float e = __expf(mx[g] - bmax[g]);
    #pragma unroll
    for (int m = 1; m <= 32; m <<= 1) e += __shfl_xor(e, m);
    if (lane == 0) red[wave][g] = e;
  }
  __syncthreads();
  if (tid < H_) {
    blkstats[((size_t)(n * COLCH + cc) * 2 + 1) * H_ + tid] =
        red[0][tid] + red[1][tid] + red[2][tid] + red[3][tid];
  }
}

// ---------------------------------------------------------------------------
// k2c: combine per-block stats -> per-(n,g) max/denom, re-read scores once,
// compute P[h], post-mix -> A2[n,g,s], written once.
// ---------------------------------------------------------------------------
__global__ __launch_bounds__(256) void k2c_a2(
    const float* __restrict__ scores, const float* __restrict__ blkstats,
    const float* __restrict__ w_pre, const float* __restrict__ w_post,
    float* __restrict__ a2out)
{
  __shared__ float wp[H_ * H_];
  __shared__ float wq[H_ * H_];
  __shared__ float mg[H_];
  __shared__ float ig[H_];
  const int n   = blockIdx.x >> 3;
  const int cc  = blockIdx.x & 7;
  const int tid = threadIdx.x;
  const float temp = 0.08838834764831845f;

  wp[tid] = w_pre[tid];
  wq[tid] = w_post[tid];
  if (tid < H_) {
    float bm[COLCH], bs[COLCH];
    #pragma unroll
    for (int c = 0; c < COLCH; ++c) {
      bm[c] = blkstats[((size_t)(n * COLCH + c) * 2 + 0) * H_ + tid];
      bs[c] = blkstats[((size_t)(n * COLCH + c) * 2 + 1) * H_ + tid];
    }
    float m = bm[0];
    #pragma unroll
    for (int c = 1; c < COLCH; ++c) m = fmaxf(m, bm[c]);
    float den = 0.0f;
    #pragma unroll
    for (int c = 0; c < COLCH; ++c) den += bs[c] * __expf(bm[c] - m);
    mg[tid] = m;
    ig[tid] = 1.0f / den;
  }
  __syncthreads();

  const float* base = scores + (size_t)n * H_ * SP1 + cc * 256 + tid;
  float sc[H_];
  #pragma unroll
  for (int h = 0; h < H_; ++h) sc[h] = base[(size_t)h * SP1];

  float P[H_];
  #pragma unroll
  for (int h = 0; h < H_; ++h) {
    float acc = 0.0f;
    #pragma unroll
    for (int h2 = 0; h2 < H_; ++h2) acc += wp[h * H_ + h2] * sc[h2];
    P[h] = __expf(acc * temp - mg[h]) * ig[h];
  }

  #pragma unroll
  for (int g = 0; g < H_; ++g) {
    float a = 0.0f;
    #pragma unroll
    for (int h = 0; h < H_; ++h) a += wq[g * H_ + h] * P[h];
    a2out[((size_t)(n * H_ + g)) * SP1 + cc * 256 + tid] = a;
  }
}

// ---------------------------------------------------------------------------
// k3: per (nh, chunk) block: load this chunk's 256 A2 weights (coalesced,
// cached), stream values_cache + appended value -> values_out (nt loads +
// nt stores), accumulate partial[d] = sum_s A2[s]*v[s,d] in registers;
// reduce through LDS to per-block partials (deterministic, no atomics).
// ---------------------------------------------------------------------------
__global__ __launch_bounds__(256) void k3_values(
    const float* __restrict__ value, const float* __restrict__ values_cache,
    const float* __restrict__ a2buf, float* __restrict__ values_out,
    float* __restrict__ partials)
{
  __shared__ float lds[8][128];
  __shared__ float a2[ROWS_PER_BLOCK];
  const int bid   = blockIdx.x;
  const int nh    = bid / CHUNKS;
  const int chunk = bid % CHUNKS;
  const int tid   = threadIdx.x;
  const int wave  = tid >> 6;
  const int lane  = tid & 63;
  const int half  = lane >> 5;
  const int lcol  = lane & 31;
  const int group = wave * 2 + half;
  const int rbase = wave * 64 + half;  // contiguous 64-row strip per wave

  a2[tid] = a2buf[(size_t)nh * SP1 + chunk * ROWS_PER_BLOCK + tid];
  __syncthreads();

  float accx = 0.0f, accy = 0.0f, accz = 0.0f, accw = 0.0f;

  #pragma unroll 8
  for (int it = 0; it < 32; ++it) {
    const int r = rbase + it * 2;
    const int s = chunk * ROWS_PER_BLOCK + r;
    const float* src = (s < S_) ? (values_cache + ((size_t)nh * S_ + s) * D_)
                                : (value + (size_t)nh * D_);
    vfloat4 v4 = __builtin_nontemporal_load(
        reinterpret_cast<const vfloat4*>(src + lcol * 4));
    __builtin_nontemporal_store(v4,
        reinterpret_cast<vfloat4*>(values_out + ((size_t)nh * SP1 + s) * D_ + lcol * 4));

    const float w = a2[r];  // broadcast within half-wave: conflict-free
    accx += w * v4.x;
    accy += w * v4.y;
    accz += w * v4.z;
    accw += w * v4.w;
  }

  lds[group][lcol * 4 + 0] = accx;
  lds[group][lcol * 4 + 1] = accy;
  lds[group][lcol * 4 + 2] = accz;
  lds[group][lcol * 4 + 3] = accw;
  __syncthreads();
  if (tid < 128) {
    float sum = 0.0f;
    #pragma unroll
    for (int gq = 0; gq < 8; ++gq) sum += lds[gq][tid];
    partials[(size_t)bid * 128 + tid] = sum;
  }
}

// ---------------------------------------------------------------------------
// k4: reduce per-chunk partials into V output. One thread per (n,h,d).
// ---------------------------------------------------------------------------
__global__ __launch_bounds__(256) void k4_reduce(
    const float* __restrict__ partials, float* __restrict__ v_out)
{
  const int g = blockIdx.x * 256 + threadIdx.x;  // NH*128
  const int nh = g >> 7;
  const int d = g & 127;
  float s = 0.0f;
  #pragma unroll
  for (int c = 0; c < CHUNKS; ++c)
    s += partials[((size_t)(nh * CHUNKS + c)) * 128 + d];
  v_out[g] = s;
}

extern "C" void kernel_launch(void* const* d_in, const int* in_sizes, int n_in,
                              void* d_out, int out_size, void* d_ws, size_t ws_size,
                              hipStream_t stream) {
  const float* query        = (const float*)d_in[0];
  const float* key          = (const float*)d_in[1];
  const float* value        = (const float*)d_in[2];
  const float* keys_cache   = (const float*)d_in[3];
  const float* values_cache = (const float*)d_in[4];
  const float* w_pre        = (const float*)d_in[5];
  const float* w_post       = (const float*)d_in[6];

  float* out = (float*)d_out;
  float* v_out      = out;                                  // [N,H,D]
  float* keys_out   = out + (size_t)NH * D_;                // [N,H,SP1,E]
  float* values_out = keys_out + (size_t)NH * SP1 * E_;     // [N,H,SP1,D]

  float* buf0     = (float*)d_ws;                 // raw scores   [NH,SP1]
  float* a2buf    = buf0 + (size_t)NH * SP1;      // A2           [NH,SP1]
  float* blkstats = a2buf + (size_t)NH * SP1;     // [N,COLCH,2,H]
  float* partials = blkstats + (size_t)N_ * COLCH * 2 * H_;  // [NH*CHUNKS,128]

  // 1. keys copy + QK scores
  k1_keys_scores<<<NH * CHUNKS, 256, 0, stream>>>(query, key, keys_cache,
                                                  keys_out, buf0);
  // 2a. per-block softmax stats (scores read once)
  k2a_stats<<<N_ * COLCH, 256, 0, stream>>>(buf0, w_pre, blkstats);
  // 2c. combine stats + compute post-mixed A2 (scores read once more)
  k2c_a2<<<N_ * COLCH, 256, 0, stream>>>(buf0, blkstats, w_pre, w_post, a2buf);
  // 3. values copy + weighted readout partials (A2 read once, coalesced)
  k3_values<<<NH * CHUNKS, 256, 0, stream>>>(value, values_cache, a2buf,
                                             values_out, partials);
  // 4. chunk-reduce -> V
  k4_reduce<<<(NH * 128) / 256, 256, 0, stream>>>(partials, v_out);
}

// Round 12
// 388.633 us; speedup vs baseline: 1.7752x; 1.0833x over previous
//
#include <hip/hip_runtime.h>
#include <cstddef>

// Problem constants (from reference setup_inputs).
constexpr int N_  = 32;
constexpr int H_  = 16;
constexpr int E_  = 128;   // = D
constexpr int D_  = 128;
constexpr int S_  = 2047;
constexpr int SP1 = 2048;  // S+1
constexpr int NH  = N_ * H_;

constexpr int ROWS_PER_BLOCK = 256;
constexpr int CHUNKS = SP1 / ROWS_PER_BLOCK;  // 8
constexpr int COLCH  = SP1 / 256;             // 8 column-chunks for k2a/k2c

typedef float vfloat4 __attribute__((ext_vector_type(4)));

// ---------------------------------------------------------------------------
// k1: stream keys_cache + appended key -> keys_out (nt loads + nt stores),
// compute scores in-pass. THIS ROUND'S ISOLATED CHANGE vs R11 (421us):
// 4-deep load batching for memory-level parallelism — issue 4 independent
// nt loads into registers, then do the 4 store+dot+reduce bodies.
// Wave-sequential mapping: each wave owns a contiguous 64-row (32KB) strip.
// No atomics anywhere (R7/R9 lesson: agent-scope fences cost ~250us).
// ---------------------------------------------------------------------------
__global__ __launch_bounds__(256) void k1_keys_scores(
    const float* __restrict__ query, const float* __restrict__ key,
    const float* __restrict__ keys_cache,
    float* __restrict__ keys_out, float* __restrict__ scores)
{
  __shared__ float sc[ROWS_PER_BLOCK];
  const int bid   = blockIdx.x;
  const int nh    = bid / CHUNKS;
  const int chunk = bid % CHUNKS;
  const int tid   = threadIdx.x;
  const int wave  = tid >> 6;
  const int lane  = tid & 63;
  const int half  = lane >> 5;
  const int lcol  = lane & 31;
  const int rbase = wave * 64 + half;  // contiguous 64-row strip per wave

  const vfloat4 q4 = *reinterpret_cast<const vfloat4*>(query + (size_t)nh * E_ + lcol * 4);

  #pragma unroll
  for (int it4 = 0; it4 < 8; ++it4) {
    vfloat4 v[4];
    // Phase A: issue 4 independent loads (deep MLP, no dependent ops between)
    #pragma unroll
    for (int j = 0; j < 4; ++j) {
      const int r = rbase + (it4 * 4 + j) * 2;
      const int s = chunk * ROWS_PER_BLOCK + r;
      const float* src = (s < S_) ? (keys_cache + ((size_t)nh * S_ + s) * E_)
                                  : (key + (size_t)nh * E_);
      v[j] = __builtin_nontemporal_load(
          reinterpret_cast<const vfloat4*>(src + lcol * 4));
    }
    // Phase B: stores + dot products + reductions
    #pragma unroll
    for (int j = 0; j < 4; ++j) {
      const int r = rbase + (it4 * 4 + j) * 2;
      const int s = chunk * ROWS_PER_BLOCK + r;
      __builtin_nontemporal_store(v[j],
          reinterpret_cast<vfloat4*>(keys_out + ((size_t)nh * SP1 + s) * E_ + lcol * 4));

      float p = q4.x * v[j].x + q4.y * v[j].y + q4.z * v[j].z + q4.w * v[j].w;
      p += __shfl_xor(p, 1);
      p += __shfl_xor(p, 2);
      p += __shfl_xor(p, 4);
      p += __shfl_xor(p, 8);
      p += __shfl_xor(p, 16);
      if (lcol == 0) sc[r] = p;
    }
  }
  __syncthreads();
  scores[(size_t)nh * SP1 + chunk * ROWS_PER_BLOCK + tid] = sc[tid];
}

// ---------------------------------------------------------------------------
// k2a: per (n, col-chunk) block, each thread owns one s column: read the 16
// head scores once, pre-mix, block-reduce per-g max and sum-exp -> stats.
// ---------------------------------------------------------------------------
__global__ __launch_bounds__(256) void k2a_stats(
    const float* __restrict__ scores, const float* __restrict__ w_pre,
    float* __restrict__ blkstats)
{
  __shared__ float wp[H_ * H_];
  __shared__ float red[4][H_];
  __shared__ float bmax[H_];
  const int n   = blockIdx.x >> 3;
  const int cc  = blockIdx.x & 7;
  const int tid = threadIdx.x;
  const int wave = tid >> 6;
  const int lane = tid & 63;
  const float temp = 0.08838834764831845f;  // 1/sqrt(128)

  wp[tid] = w_pre[tid];
  __syncthreads();

  const float* base = scores + (size_t)n * H_ * SP1 + cc * 256 + tid;
  float sc[H_];
  #pragma unroll
  for (int h = 0; h < H_; ++h) sc[h] = base[(size_t)h * SP1];

  float mx[H_];
  #pragma unroll
  for (int g = 0; g < H_; ++g) {
    float acc = 0.0f;
    #pragma unroll
    for (int h = 0; h < H_; ++h) acc += wp[g * H_ + h] * sc[h];
    mx[g] = acc * temp;
  }

  #pragma unroll
  for (int g = 0; g < H_; ++g) {
    float v = mx[g];
    #pragma unroll
    for (int m = 1; m <= 32; m <<= 1) v = fmaxf(v, __shfl_xor(v, m));
    if (lane == 0) red[wave][g] = v;
  }
  __syncthreads();
  if (tid < H_) {
    float v = fmaxf(fmaxf(red[0][tid], red[1][tid]), fmaxf(red[2][tid], red[3][tid]));
    bmax[tid] = v;
    blkstats[((size_t)(n * COLCH + cc) * 2 + 0) * H_ + tid] = v;
  }
  __syncthreads();

  #pragma unroll
  for (int g = 0; g < H_; ++g) {
    float e = __expf(mx[g] - bmax[g]);
    #pragma unroll
    for (int m = 1; m <= 32; m <<= 1) e += __shfl_xor(e, m);
    if (lane == 0) red[wave][g] = e;
  }
  __syncthreads();
  if (tid < H_) {
    blkstats[((size_t)(n * COLCH + cc) * 2 + 1) * H_ + tid] =
        red[0][tid] + red[1][tid] + red[2][tid] + red[3][tid];
  }
}

// ---------------------------------------------------------------------------
// k2c: combine per-block stats -> per-(n,g) max/denom, re-read scores once,
// compute P[h], post-mix -> A2[n,g,s], written once.
// ---------------------------------------------------------------------------
__global__ __launch_bounds__(256) void k2c_a2(
    const float* __restrict__ scores, const float* __restrict__ blkstats,
    const float* __restrict__ w_pre, const float* __restrict__ w_post,
    float* __restrict__ a2out)
{
  __shared__ float wp[H_ * H_];
  __shared__ float wq[H_ * H_];
  __shared__ float mg[H_];
  __shared__ float ig[H_];
  const int n   = blockIdx.x >> 3;
  const int cc  = blockIdx.x & 7;
  const int tid = threadIdx.x;
  const float temp = 0.08838834764831845f;

  wp[tid] = w_pre[tid];
  wq[tid] = w_post[tid];
  if (tid < H_) {
    float bm[COLCH], bs[COLCH];
    #pragma unroll
    for (int c = 0; c < COLCH; ++c) {
      bm[c] = blkstats[((size_t)(n * COLCH + c) * 2 + 0) * H_ + tid];
      bs[c] = blkstats[((size_t)(n * COLCH + c) * 2 + 1) * H_ + tid];
    }
    float m = bm[0];
    #pragma unroll
    for (int c = 1; c < COLCH; ++c) m = fmaxf(m, bm[c]);
    float den = 0.0f;
    #pragma unroll
    for (int c = 0; c < COLCH; ++c) den += bs[c] * __expf(bm[c] - m);
    mg[tid] = m;
    ig[tid] = 1.0f / den;
  }
  __syncthreads();

  const float* base = scores + (size_t)n * H_ * SP1 + cc * 256 + tid;
  float sc[H_];
  #pragma unroll
  for (int h = 0; h < H_; ++h) sc[h] = base[(size_t)h * SP1];

  float P[H_];
  #pragma unroll
  for (int h = 0; h < H_; ++h) {
    float acc = 0.0f;
    #pragma unroll
    for (int h2 = 0; h2 < H_; ++h2) acc += wp[h * H_ + h2] * sc[h2];
    P[h] = __expf(acc * temp - mg[h]) * ig[h];
  }

  #pragma unroll
  for (int g = 0; g < H_; ++g) {
    float a = 0.0f;
    #pragma unroll
    for (int h = 0; h < H_; ++h) a += wq[g * H_ + h] * P[h];
    a2out[((size_t)(n * H_ + g)) * SP1 + cc * 256 + tid] = a;
  }
}

// ---------------------------------------------------------------------------
// k3: per (nh, chunk) block: load this chunk's 256 A2 weights (coalesced,
// cached), stream values_cache + appended value -> values_out (nt loads +
// nt stores, 4-deep load batching), accumulate partial[d] = sum_s A2[s]*v[s,d]
// in registers; reduce through LDS to per-block partials (no atomics).
// ---------------------------------------------------------------------------
__global__ __launch_bounds__(256) void k3_values(
    const float* __restrict__ value, const float* __restrict__ values_cache,
    const float* __restrict__ a2buf, float* __restrict__ values_out,
    float* __restrict__ partials)
{
  __shared__ float lds[8][128];
  __shared__ float a2[ROWS_PER_BLOCK];
  const int bid   = blockIdx.x;
  const int nh    = bid / CHUNKS;
  const int chunk = bid % CHUNKS;
  const int tid   = threadIdx.x;
  const int wave  = tid >> 6;
  const int lane  = tid & 63;
  const int half  = lane >> 5;
  const int lcol  = lane & 31;
  const int group = wave * 2 + half;
  const int rbase = wave * 64 + half;  // contiguous 64-row strip per wave

  a2[tid] = a2buf[(size_t)nh * SP1 + chunk * ROWS_PER_BLOCK + tid];
  __syncthreads();

  float accx = 0.0f, accy = 0.0f, accz = 0.0f, accw = 0.0f;

  #pragma unroll
  for (int it4 = 0; it4 < 8; ++it4) {
    vfloat4 v[4];
    // Phase A: issue 4 independent loads
    #pragma unroll
    for (int j = 0; j < 4; ++j) {
      const int r = rbase + (it4 * 4 + j) * 2;
      const int s = chunk * ROWS_PER_BLOCK + r;
      const float* src = (s < S_) ? (values_cache + ((size_t)nh * S_ + s) * D_)
                                  : (value + (size_t)nh * D_);
      v[j] = __builtin_nontemporal_load(
          reinterpret_cast<const vfloat4*>(src + lcol * 4));
    }
    // Phase B: stores + weighted accumulation
    #pragma unroll
    for (int j = 0; j < 4; ++j) {
      const int r = rbase + (it4 * 4 + j) * 2;
      const int s = chunk * ROWS_PER_BLOCK + r;
      __builtin_nontemporal_store(v[j],
          reinterpret_cast<vfloat4*>(values_out + ((size_t)nh * SP1 + s) * D_ + lcol * 4));

      const float w = a2[r];  // broadcast within half-wave: conflict-free
      accx += w * v[j].x;
      accy += w * v[j].y;
      accz += w * v[j].z;
      accw += w * v[j].w;
    }
  }

  lds[group][lcol * 4 + 0] = accx;
  lds[group][lcol * 4 + 1] = accy;
  lds[group][lcol * 4 + 2] = accz;
  lds[group][lcol * 4 + 3] = accw;
  __syncthreads();
  if (tid < 128) {
    float sum = 0.0f;
    #pragma unroll
    for (int gq = 0; gq < 8; ++gq) sum += lds[gq][tid];
    partials[(size_t)bid * 128 + tid] = sum;
  }
}

// ---------------------------------------------------------------------------
// k4: reduce per-chunk partials into V output. One thread per (n,h,d).
// ---------------------------------------------------------------------------
__global__ __launch_bounds__(256) void k4_reduce(
    const float* __restrict__ partials, float* __restrict__ v_out)
{
  const int g = blockIdx.x * 256 + threadIdx.x;  // NH*128
  const int nh = g >> 7;
  const int d = g & 127;
  float s = 0.0f;
  #pragma unroll
  for (int c = 0; c < CHUNKS; ++c)
    s += partials[((size_t)(nh * CHUNKS + c)) * 128 + d];
  v_out[g] = s;
}

extern "C" void kernel_launch(void* const* d_in, const int* in_sizes, int n_in,
                              void* d_out, int out_size, void* d_ws, size_t ws_size,
                              hipStream_t stream) {
  const float* query        = (const float*)d_in[0];
  const float* key          = (const float*)d_in[1];
  const float* value        = (const float*)d_in[2];
  const float* keys_cache   = (const float*)d_in[3];
  const float* values_cache = (const float*)d_in[4];
  const float* w_pre        = (const float*)d_in[5];
  const float* w_post       = (const float*)d_in[6];

  float* out = (float*)d_out;
  float* v_out      = out;                                  // [N,H,D]
  float* keys_out   = out + (size_t)NH * D_;                // [N,H,SP1,E]
  float* values_out = keys_out + (size_t)NH * SP1 * E_;     // [N,H,SP1,D]

  float* buf0     = (float*)d_ws;                 // raw scores   [NH,SP1]
  float* a2buf    = buf0 + (size_t)NH * SP1;      // A2           [NH,SP1]
  float* blkstats = a2buf + (size_t)NH * SP1;     // [N,COLCH,2,H]
  float* partials = blkstats + (size_t)N_ * COLCH * 2 * H_;  // [NH*CHUNKS,128]

  // 1. keys copy + QK scores
  k1_keys_scores<<<NH * CHUNKS, 256, 0, stream>>>(query, key, keys_cache,
                                                  keys_out, buf0);
  // 2a. per-block softmax stats (scores read once)
  k2a_stats<<<N_ * COLCH, 256, 0, stream>>>(buf0, w_pre, blkstats);
  // 2c. combine stats + compute post-mixed A2 (scores read once more)
  k2c_a2<<<N_ * COLCH, 256, 0, stream>>>(buf0, blkstats, w_pre, w_post, a2buf);
  // 3. values copy + weighted readout partials (A2 read once, coalesced)
  k3_values<<<NH * CHUNKS, 256, 0, stream>>>(value, values_cache, a2buf,
                                             values_out, partials);
  // 4. chunk-reduce -> V
  k4_reduce<<<(NH * 128) / 256, 256, 0, stream>>>(partials, v_out);
}

// Round 13
// 384.603 us; speedup vs baseline: 1.7938x; 1.0105x over previous
//
#include <hip/hip_runtime.h>
#include <cstddef>

// Problem constants (from reference setup_inputs).
constexpr int N_  = 32;
constexpr int H_  = 16;
constexpr int E_  = 128;   // = D
constexpr int D_  = 128;
constexpr int S_  = 2047;
constexpr int SP1 = 2048;  // S+1
constexpr int NH  = N_ * H_;

constexpr int ROWS_PER_BLOCK = 256;
constexpr int CHUNKS = SP1 / ROWS_PER_BLOCK;  // 8
constexpr int COLCH  = SP1 / 256;             // 8 column-chunks for k2a/k2c

typedef float vfloat4 __attribute__((ext_vector_type(4)));

// ---------------------------------------------------------------------------
// k1: stream keys_cache + appended key -> keys_out (nt loads + nt stores),
// compute scores in-pass. THIS ROUND'S ISOLATED CHANGE vs R12 (388us):
// batch depth 4 -> 8 (issue 8 independent nt loads, then 8 bodies).
// Wave-sequential mapping: each wave owns a contiguous 64-row (32KB) strip.
// No atomics anywhere (R7/R9 lesson: agent-scope fences cost ~250us).
// ---------------------------------------------------------------------------
__global__ __launch_bounds__(256) void k1_keys_scores(
    const float* __restrict__ query, const float* __restrict__ key,
    const float* __restrict__ keys_cache,
    float* __restrict__ keys_out, float* __restrict__ scores)
{
  __shared__ float sc[ROWS_PER_BLOCK];
  const int bid   = blockIdx.x;
  const int nh    = bid / CHUNKS;
  const int chunk = bid % CHUNKS;
  const int tid   = threadIdx.x;
  const int wave  = tid >> 6;
  const int lane  = tid & 63;
  const int half  = lane >> 5;
  const int lcol  = lane & 31;
  const int rbase = wave * 64 + half;  // contiguous 64-row strip per wave

  const vfloat4 q4 = *reinterpret_cast<const vfloat4*>(query + (size_t)nh * E_ + lcol * 4);

  #pragma unroll
  for (int it8 = 0; it8 < 4; ++it8) {
    vfloat4 v[8];
    // Phase A: issue 8 independent loads (deep MLP)
    #pragma unroll
    for (int j = 0; j < 8; ++j) {
      const int r = rbase + (it8 * 8 + j) * 2;
      const int s = chunk * ROWS_PER_BLOCK + r;
      const float* src = (s < S_) ? (keys_cache + ((size_t)nh * S_ + s) * E_)
                                  : (key + (size_t)nh * E_);
      v[j] = __builtin_nontemporal_load(
          reinterpret_cast<const vfloat4*>(src + lcol * 4));
    }
    // Phase B: stores + dot products + reductions
    #pragma unroll
    for (int j = 0; j < 8; ++j) {
      const int r = rbase + (it8 * 8 + j) * 2;
      const int s = chunk * ROWS_PER_BLOCK + r;
      __builtin_nontemporal_store(v[j],
          reinterpret_cast<vfloat4*>(keys_out + ((size_t)nh * SP1 + s) * E_ + lcol * 4));

      float p = q4.x * v[j].x + q4.y * v[j].y + q4.z * v[j].z + q4.w * v[j].w;
      p += __shfl_xor(p, 1);
      p += __shfl_xor(p, 2);
      p += __shfl_xor(p, 4);
      p += __shfl_xor(p, 8);
      p += __shfl_xor(p, 16);
      if (lcol == 0) sc[r] = p;
    }
  }
  __syncthreads();
  scores[(size_t)nh * SP1 + chunk * ROWS_PER_BLOCK + tid] = sc[tid];
}

// ---------------------------------------------------------------------------
// k2a: per (n, col-chunk) block, each thread owns one s column: read the 16
// head scores once, pre-mix, block-reduce per-g max and sum-exp -> stats.
// ---------------------------------------------------------------------------
__global__ __launch_bounds__(256) void k2a_stats(
    const float* __restrict__ scores, const float* __restrict__ w_pre,
    float* __restrict__ blkstats)
{
  __shared__ float wp[H_ * H_];
  __shared__ float red[4][H_];
  __shared__ float bmax[H_];
  const int n   = blockIdx.x >> 3;
  const int cc  = blockIdx.x & 7;
  const int tid = threadIdx.x;
  const int wave = tid >> 6;
  const int lane = tid & 63;
  const float temp = 0.08838834764831845f;  // 1/sqrt(128)

  wp[tid] = w_pre[tid];
  __syncthreads();

  const float* base = scores + (size_t)n * H_ * SP1 + cc * 256 + tid;
  float sc[H_];
  #pragma unroll
  for (int h = 0; h < H_; ++h) sc[h] = base[(size_t)h * SP1];

  float mx[H_];
  #pragma unroll
  for (int g = 0; g < H_; ++g) {
    float acc = 0.0f;
    #pragma unroll
    for (int h = 0; h < H_; ++h) acc += wp[g * H_ + h] * sc[h];
    mx[g] = acc * temp;
  }

  #pragma unroll
  for (int g = 0; g < H_; ++g) {
    float v = mx[g];
    #pragma unroll
    for (int m = 1; m <= 32; m <<= 1) v = fmaxf(v, __shfl_xor(v, m));
    if (lane == 0) red[wave][g] = v;
  }
  __syncthreads();
  if (tid < H_) {
    float v = fmaxf(fmaxf(red[0][tid], red[1][tid]), fmaxf(red[2][tid], red[3][tid]));
    bmax[tid] = v;
    blkstats[((size_t)(n * COLCH + cc) * 2 + 0) * H_ + tid] = v;
  }
  __syncthreads();

  #pragma unroll
  for (int g = 0; g < H_; ++g) {
    float e = __expf(mx[g] - bmax[g]);
    #pragma unroll
    for (int m = 1; m <= 32; m <<= 1) e += __shfl_xor(e, m);
    if (lane == 0) red[wave][g] = e;
  }
  __syncthreads();
  if (tid < H_) {
    blkstats[((size_t)(n * COLCH + cc) * 2 + 1) * H_ + tid] =
        red[0][tid] + red[1][tid] + red[2][tid] + red[3][tid];
  }
}

// ---------------------------------------------------------------------------
// k2c: combine per-block stats -> per-(n,g) max/denom, re-read scores once,
// compute P[h], post-mix -> A2[n,g,s], written once.
// ---------------------------------------------------------------------------
__global__ __launch_bounds__(256) void k2c_a2(
    const float* __restrict__ scores, const float* __restrict__ blkstats,
    const float* __restrict__ w_pre, const float* __restrict__ w_post,
    float* __restrict__ a2out)
{
  __shared__ float wp[H_ * H_];
  __shared__ float wq[H_ * H_];
  __shared__ float mg[H_];
  __shared__ float ig[H_];
  const int n   = blockIdx.x >> 3;
  const int cc  = blockIdx.x & 7;
  const int tid = threadIdx.x;
  const float temp = 0.08838834764831845f;

  wp[tid] = w_pre[tid];
  wq[tid] = w_post[tid];
  if (tid < H_) {
    float bm[COLCH], bs[COLCH];
    #pragma unroll
    for (int c = 0; c < COLCH; ++c) {
      bm[c] = blkstats[((size_t)(n * COLCH + c) * 2 + 0) * H_ + tid];
      bs[c] = blkstats[((size_t)(n * COLCH + c) * 2 + 1) * H_ + tid];
    }
    float m = bm[0];
    #pragma unroll
    for (int c = 1; c < COLCH; ++c) m = fmaxf(m, bm[c]);
    float den = 0.0f;
    #pragma unroll
    for (int c = 0; c < COLCH; ++c) den += bs[c] * __expf(bm[c] - m);
    mg[tid] = m;
    ig[tid] = 1.0f / den;
  }
  __syncthreads();

  const float* base = scores + (size_t)n * H_ * SP1 + cc * 256 + tid;
  float sc[H_];
  #pragma unroll
  for (int h = 0; h < H_; ++h) sc[h] = base[(size_t)h * SP1];

  float P[H_];
  #pragma unroll
  for (int h = 0; h < H_; ++h) {
    float acc = 0.0f;
    #pragma unroll
    for (int h2 = 0; h2 < H_; ++h2) acc += wp[h * H_ + h2] * sc[h2];
    P[h] = __expf(acc * temp - mg[h]) * ig[h];
  }

  #pragma unroll
  for (int g = 0; g < H_; ++g) {
    float a = 0.0f;
    #pragma unroll
    for (int h = 0; h < H_; ++h) a += wq[g * H_ + h] * P[h];
    a2out[((size_t)(n * H_ + g)) * SP1 + cc * 256 + tid] = a;
  }
}

// ---------------------------------------------------------------------------
// k3: per (nh, chunk) block: load this chunk's 256 A2 weights (coalesced,
// cached), stream values_cache + appended value -> values_out (nt loads +
// nt stores, 8-deep load batching), accumulate partial[d] = sum_s A2[s]*v[s,d]
// in registers; reduce through LDS to per-block partials (no atomics).
// ---------------------------------------------------------------------------
__global__ __launch_bounds__(256) void k3_values(
    const float* __restrict__ value, const float* __restrict__ values_cache,
    const float* __restrict__ a2buf, float* __restrict__ values_out,
    float* __restrict__ partials)
{
  __shared__ float lds[8][128];
  __shared__ float a2[ROWS_PER_BLOCK];
  const int bid   = blockIdx.x;
  const int nh    = bid / CHUNKS;
  const int chunk = bid % CHUNKS;
  const int tid   = threadIdx.x;
  const int wave  = tid >> 6;
  const int lane  = tid & 63;
  const int half  = lane >> 5;
  const int lcol  = lane & 31;
  const int group = wave * 2 + half;
  const int rbase = wave * 64 + half;  // contiguous 64-row strip per wave

  a2[tid] = a2buf[(size_t)nh * SP1 + chunk * ROWS_PER_BLOCK + tid];
  __syncthreads();

  float accx = 0.0f, accy = 0.0f, accz = 0.0f, accw = 0.0f;

  #pragma unroll
  for (int it8 = 0; it8 < 4; ++it8) {
    vfloat4 v[8];
    // Phase A: issue 8 independent loads
    #pragma unroll
    for (int j = 0; j < 8; ++j) {
      const int r = rbase + (it8 * 8 + j) * 2;
      const int s = chunk * ROWS_PER_BLOCK + r;
      const float* src = (s < S_) ? (values_cache + ((size_t)nh * S_ + s) * D_)
                                  : (value + (size_t)nh * D_);
      v[j] = __builtin_nontemporal_load(
          reinterpret_cast<const vfloat4*>(src + lcol * 4));
    }
    // Phase B: stores + weighted accumulation
    #pragma unroll
    for (int j = 0; j < 8; ++j) {
      const int r = rbase + (it8 * 8 + j) * 2;
      const int s = chunk * ROWS_PER_BLOCK + r;
      __builtin_nontemporal_store(v[j],
          reinterpret_cast<vfloat4*>(values_out + ((size_t)nh * SP1 + s) * D_ + lcol * 4));

      const float w = a2[r];  // broadcast within half-wave: conflict-free
      accx += w * v[j].x;
      accy += w * v[j].y;
      accz += w * v[j].z;
      accw += w * v[j].w;
    }
  }

  lds[group][lcol * 4 + 0] = accx;
  lds[group][lcol * 4 + 1] = accy;
  lds[group][lcol * 4 + 2] = accz;
  lds[group][lcol * 4 + 3] = accw;
  __syncthreads();
  if (tid < 128) {
    float sum = 0.0f;
    #pragma unroll
    for (int gq = 0; gq < 8; ++gq) sum += lds[gq][tid];
    partials[(size_t)bid * 128 + tid] = sum;
  }
}

// ---------------------------------------------------------------------------
// k4: reduce per-chunk partials into V output. One thread per (n,h,d).
// ---------------------------------------------------------------------------
__global__ __launch_bounds__(256) void k4_reduce(
    const float* __restrict__ partials, float* __restrict__ v_out)
{
  const int g = blockIdx.x * 256 + threadIdx.x;  // NH*128
  const int nh = g >> 7;
  const int d = g & 127;
  float s = 0.0f;
  #pragma unroll
  for (int c = 0; c < CHUNKS; ++c)
    s += partials[((size_t)(nh * CHUNKS + c)) * 128 + d];
  v_out[g] = s;
}

extern "C" void kernel_launch(void* const* d_in, const int* in_sizes, int n_in,
                              void* d_out, int out_size, void* d_ws, size_t ws_size,
                              hipStream_t stream) {
  const float* query        = (const float*)d_in[0];
  const float* key          = (const float*)d_in[1];
  const float* value        = (const float*)d_in[2];
  const float* keys_cache   = (const float*)d_in[3];
  const float* values_cache = (const float*)d_in[4];
  const float* w_pre        = (const float*)d_in[5];
  const float* w_post       = (const float*)d_in[6];

  float* out = (float*)d_out;
  float* v_out      = out;                                  // [N,H,D]
  float* keys_out   = out + (size_t)NH * D_;                // [N,H,SP1,E]
  float* values_out = keys_out + (size_t)NH * SP1 * E_;     // [N,H,SP1,D]

  float* buf0     = (float*)d_ws;                 // raw scores   [NH,SP1]
  float* a2buf    = buf0 + (size_t)NH * SP1;      // A2           [NH,SP1]
  float* blkstats = a2buf + (size_t)NH * SP1;     // [N,COLCH,2,H]
  float* partials = blkstats + (size_t)N_ * COLCH * 2 * H_;  // [NH*CHUNKS,128]

  // 1. keys copy + QK scores
  k1_keys_scores<<<NH * CHUNKS, 256, 0, stream>>>(query, key, keys_cache,
                                                  keys_out, buf0);
  // 2a. per-block softmax stats (scores read once)
  k2a_stats<<<N_ * COLCH, 256, 0, stream>>>(buf0, w_pre, blkstats);
  // 2c. combine stats + compute post-mixed A2 (scores read once more)
  k2c_a2<<<N_ * COLCH, 256, 0, stream>>>(buf0, blkstats, w_pre, w_post, a2buf);
  // 3. values copy + weighted readout partials (A2 read once, coalesced)
  k3_values<<<NH * CHUNKS, 256, 0, stream>>>(value, values_cache, a2buf,
                                             values_out, partials);
  // 4. chunk-reduce -> V
  k4_reduce<<<(NH * 128) / 256, 256, 0, stream>>>(partials, v_out);
}